// Round 1
// baseline (405.838 us; speedup 1.0000x reference)
//
#include <hip/hip_runtime.h>
#include <hip/hip_bf16.h>
#include <math.h>
#include <stdint.h>

// Problem constants (fixed by the reference setup)
#define H     256      // hidden
#define K2    512      // fused K = 2H
#define SDEC  2048     // decoder sequence length S
#define LCSH  14       // log2(Lc) = log2(16384)
#define BM    64       // rows per block
#define BK    64       // K-tile
#define NTHR  256

typedef __attribute__((ext_vector_type(8))) short  short8;
typedef __attribute__((ext_vector_type(4))) float  f32x4;

typedef __attribute__((address_space(3))) unsigned int lds_u32;
typedef __attribute__((address_space(1))) unsigned int glb_u32;

__device__ __forceinline__ void async_ld16(const void* g, void* l) {
  // global -> LDS direct copy, 16B per lane; LDS dest = wave-uniform base + lane*16
  __builtin_amdgcn_global_load_lds((const glb_u32*)(uintptr_t)g,
                                   (lds_u32*)(uintptr_t)l, 16, 0, 0);
}

__device__ __forceinline__ unsigned short f2bf(float f) {
  union { float f; unsigned int u; } c; c.f = f;
  unsigned int u = c.u;
  unsigned int r = u + 0x7fffu + ((u >> 16) & 1u);   // round-to-nearest-even
  return (unsigned short)(r >> 16);
}

// ---------------------------------------------------------------------------
// Prep kernel 1: fused transposed weights (bf16)
//   T[k][n] = sum_j W1[k][j] * W2[256+j][n]          (k in [0,512))
//   WfT[n][k] = bf16( T[k][n] + (k<256 ? W2[k][n] : 0) )
// Grid: 8 k-tiles x 4 n-tiles = 32 blocks, 256 threads, 64x64 tiles.
// ---------------------------------------------------------------------------
__global__ __launch_bounds__(256) void fuse_weights(
    const float* __restrict__ W1, const float* __restrict__ W2,
    unsigned short* __restrict__ wft) {
  __shared__ float As[64][65];
  __shared__ float Bs[64][65];
  const int t  = threadIdx.x;
  const int k0 = (blockIdx.x >> 2) * 64;
  const int n0 = (blockIdx.x & 3) * 64;
  const int lr = t >> 2;     // staging row 0..63
  const int ls = t & 3;      // staging 16-float segment
  const int tk = t >> 4;     // compute k sub-tile 0..15
  const int tn = t & 15;     // compute n sub-tile 0..15

  float acc[4][4];
#pragma unroll
  for (int i = 0; i < 4; ++i)
#pragma unroll
    for (int c = 0; c < 4; ++c) acc[i][c] = 0.0f;

  for (int jt = 0; jt < 4; ++jt) {
    const int j0 = jt * 64;
    __syncthreads();
    const float* a_src = W1 + (size_t)(k0 + lr) * H + j0 + ls * 16;
    const float* b_src = W2 + (size_t)(H + j0 + lr) * H + n0 + ls * 16;
#pragma unroll
    for (int i = 0; i < 16; ++i) {
      As[lr][ls * 16 + i] = a_src[i];
      Bs[lr][ls * 16 + i] = b_src[i];
    }
    __syncthreads();
#pragma unroll 8
    for (int j = 0; j < 64; ++j) {
      float a[4], b[4];
#pragma unroll
      for (int i = 0; i < 4; ++i) a[i] = As[tk * 4 + i][j];
#pragma unroll
      for (int c = 0; c < 4; ++c) b[c] = Bs[j][tn * 4 + c];
#pragma unroll
      for (int i = 0; i < 4; ++i)
#pragma unroll
        for (int c = 0; c < 4; ++c) acc[i][c] += a[i] * b[c];
    }
  }

#pragma unroll
  for (int i = 0; i < 4; ++i) {
    const int k = k0 + tk * 4 + i;
#pragma unroll
    for (int c = 0; c < 4; ++c) {
      const int n = n0 + tn * 4 + c;
      float v = acc[i][c];
      if (k < H) v += W2[(size_t)k * H + n];
      wft[(size_t)n * K2 + k] = f2bf(v);
    }
  }
}

// ---------------------------------------------------------------------------
// Prep kernel 2: fused bias  biasf[n] = b2[n] + sum_j b1[j]*W2[256+j][n]
// ---------------------------------------------------------------------------
__global__ __launch_bounds__(256) void fuse_bias(
    const float* __restrict__ W2, const float* __restrict__ b1,
    const float* __restrict__ b2, float* __restrict__ biasf) {
  const int n = threadIdx.x;
  float acc = b2[n];
  for (int j = 0; j < H; ++j) acc += b1[j] * W2[(size_t)(H + j) * H + n];
  biasf[n] = acc;
}

// ---------------------------------------------------------------------------
// Main kernel: per 64-row block — fused GEMM (bf16 MFMA) + bias + LN + GELU +
// residual. N=256 is block-local so LayerNorm reduces inside the block.
// ---------------------------------------------------------------------------
__global__ __launch_bounds__(NTHR, 2) void syl_main(
    const float* __restrict__ cemb, const int* __restrict__ tal,
    const float* __restrict__ dec, const unsigned short* __restrict__ wft,
    const float* __restrict__ biasf, const float* __restrict__ gamma,
    const float* __restrict__ beta, float* __restrict__ out) {

  __shared__ __align__(16) unsigned short Ash[BM][72];   // +8 pad, 9.2 KB
  __shared__ __align__(16) unsigned short Bsh[H][BK];    // [n][k] 32 KB, NO pad (global_load_lds)
  __shared__ int   idxs[BM];
  __shared__ float msks[BM];
  __shared__ float stats[4][BM][2];

  const int t    = threadIdx.x;
  const int wave = t >> 6;
  const int lane = t & 63;
  const int quad = lane >> 4;
  const int l15  = lane & 15;
  const int row0 = blockIdx.x * BM;
  const int bidx = row0 >> LCSH;
  const float* decb = dec + (size_t)bidx * SDEC * H;

  if (t < BM) {
    int ix = tal[row0 + t];
    idxs[t] = ix < 0 ? 0 : (ix >= SDEC ? SDEC - 1 : ix);
    msks[t] = ix < 0 ? 0.0f : 1.0f;
  }

  f32x4 acc[4][4];
#pragma unroll
  for (int m = 0; m < 4; ++m)
#pragma unroll
    for (int n = 0; n < 4; ++n) acc[m][n] = (f32x4){0.f, 0.f, 0.f, 0.f};

  const int srow = t >> 2;   // A-staging row 0..63
  const int sseg = t & 3;    // 16-float segment

  for (int ki = 0; ki < 8; ++ki) {
    const int k0 = ki * BK;

    // ---- stage B tile [n][k_local] via async global->LDS (bf16, 16B/lane)
#pragma unroll
    for (int c = 0; c < 8; ++c) {
      const int nrow = wave * 64 + c * 8;           // wave-uniform
      const unsigned short* g =
          wft + (size_t)(nrow + (lane >> 3)) * K2 + k0 + (lane & 7) * 8;
      async_ld16(g, &Bsh[nrow][0]);
    }

    // ---- stage A tile: fp32 global -> bf16 LDS (char rows then gathered tok)
    const float* src;
    float scale;
    if (k0 < H) {
      src = cemb + (size_t)(row0 + srow) * H + k0 + sseg * 16;
      scale = 1.0f;
    } else {
      src = decb + (size_t)idxs[srow] * H + (k0 - H) + sseg * 16;
      scale = msks[srow];
    }
    float4 f[4];
#pragma unroll
    for (int q = 0; q < 4; ++q) f[q] = *(const float4*)(src + q * 4);
    unsigned short hb[16];
#pragma unroll
    for (int q = 0; q < 4; ++q) {
      hb[q * 4 + 0] = f2bf(f[q].x * scale);
      hb[q * 4 + 1] = f2bf(f[q].y * scale);
      hb[q * 4 + 2] = f2bf(f[q].z * scale);
      hb[q * 4 + 3] = f2bf(f[q].w * scale);
    }
    *(short8*)&Ash[srow][sseg * 16]     = *(short8*)&hb[0];
    *(short8*)&Ash[srow][sseg * 16 + 8] = *(short8*)&hb[8];

    __syncthreads();   // drains vmcnt (global_load_lds) + lgkmcnt

    // ---- MFMA: wave computes 64 rows x 64 cols, K=64 (2 k-steps)
    short8 af[2][4];
#pragma unroll
    for (int ks = 0; ks < 2; ++ks)
#pragma unroll
      for (int m = 0; m < 4; ++m)
        af[ks][m] = *(const short8*)&Ash[m * 16 + l15][ks * 32 + quad * 8];
#pragma unroll
    for (int ks = 0; ks < 2; ++ks)
#pragma unroll
      for (int n = 0; n < 4; ++n) {
        short8 bf = *(const short8*)&Bsh[wave * 64 + n * 16 + l15][ks * 32 + quad * 8];
#pragma unroll
        for (int m = 0; m < 4; ++m)
          acc[m][n] = __builtin_amdgcn_mfma_f32_16x16x32_bf16(
              af[ks][m], bf, acc[m][n], 0, 0, 0);
      }
    __syncthreads();   // protect LDS before next iteration's staging
  }

  // ---- epilogue: bias, LN stats, LN + exact GELU + residual
  float bvals[4], gvals[4], betv[4];
#pragma unroll
  for (int n = 0; n < 4; ++n) {
    const int col = wave * 64 + n * 16 + l15;
    bvals[n] = biasf[col];
    gvals[n] = gamma[col];
    betv[n]  = beta[col];
  }
#pragma unroll
  for (int m = 0; m < 4; ++m)
#pragma unroll
    for (int n = 0; n < 4; ++n)
#pragma unroll
      for (int r = 0; r < 4; ++r) acc[m][n][r] += bvals[n];

  // per-row partial sums over this wave's 64 columns
#pragma unroll
  for (int m = 0; m < 4; ++m)
#pragma unroll
    for (int r = 0; r < 4; ++r) {
      float a = 0.f, b = 0.f;
#pragma unroll
      for (int n = 0; n < 4; ++n) {
        const float v = acc[m][n][r];
        a += v; b += v * v;
      }
#pragma unroll
      for (int d = 1; d < 16; d <<= 1) {   // butterfly within quad (cols)
        a += __shfl_xor(a, d, 64);
        b += __shfl_xor(b, d, 64);
      }
      if (l15 == 0) {
        const int row = m * 16 + quad * 4 + r;
        stats[wave][row][0] = a;
        stats[wave][row][1] = b;
      }
    }
  __syncthreads();

  float mean_[4][4], rstd_[4][4];
#pragma unroll
  for (int m = 0; m < 4; ++m)
#pragma unroll
    for (int r = 0; r < 4; ++r) {
      const int row = m * 16 + quad * 4 + r;
      const float a = stats[0][row][0] + stats[1][row][0] +
                      stats[2][row][0] + stats[3][row][0];
      const float b = stats[0][row][1] + stats[1][row][1] +
                      stats[2][row][1] + stats[3][row][1];
      const float mu  = a * (1.0f / 256.0f);
      const float var = b * (1.0f / 256.0f) - mu * mu;
      mean_[m][r] = mu;
      rstd_[m][r] = rsqrtf(var + 1e-5f);
    }

#pragma unroll
  for (int m = 0; m < 4; ++m) {
#pragma unroll
    for (int r = 0; r < 4; ++r) {
      const size_t row = (size_t)row0 + m * 16 + quad * 4 + r;
      const float* crow = cemb + row * H;
      float* orow = out + row * H;
#pragma unroll
      for (int n = 0; n < 4; ++n) {
        const int col = wave * 64 + n * 16 + l15;
        const float x = (acc[m][n][r] - mean_[m][r]) * rstd_[m][r];
        const float y = x * gvals[n] + betv[n];
        const float g = 0.5f * y * (1.0f + erff(y * 0.70710678118654752f));
        orow[col] = crow[col] + g;
      }
    }
  }
}

extern "C" void kernel_launch(void* const* d_in, const int* in_sizes, int n_in,
                              void* d_out, int out_size, void* d_ws, size_t ws_size,
                              hipStream_t stream) {
  const float* cemb  = (const float*)d_in[0];
  const int*   tal   = (const int*)d_in[1];
  const float* dec   = (const float*)d_in[2];
  const float* W1    = (const float*)d_in[3];
  const float* b1    = (const float*)d_in[4];
  const float* W2    = (const float*)d_in[5];
  const float* b2    = (const float*)d_in[6];
  const float* gamma = (const float*)d_in[7];
  const float* beta  = (const float*)d_in[8];
  float* out = (float*)d_out;

  unsigned short* wft = (unsigned short*)d_ws;                       // 256 KB bf16 WfT[256][512]
  float* biasf = (float*)((char*)d_ws + (size_t)K2 * H * sizeof(unsigned short));

  const int rows = in_sizes[0] / H;   // 131072

  hipLaunchKernelGGL(fuse_weights, dim3(32), dim3(256), 0, stream, W1, W2, wft);
  hipLaunchKernelGGL(fuse_bias, dim3(1), dim3(256), 0, stream, W2, b1, b2, biasf);
  hipLaunchKernelGGL(syl_main, dim3(rows / BM), dim3(NTHR), 0, stream,
                     cemb, tal, dec, wft, biasf, gamma, beta, out);
}

// Round 2
// 401.708 us; speedup vs baseline: 1.0103x; 1.0103x over previous
//
#include <hip/hip_runtime.h>
#include <hip/hip_bf16.h>
#include <math.h>
#include <stdint.h>

#define H     256
#define K2    512
#define SDEC  2048
#define LCSH  14
#define BM    64
#define BK    64
#define NTHR  256

typedef __attribute__((ext_vector_type(8))) short  short8;
typedef __attribute__((ext_vector_type(4))) float  f32x4;

__device__ __forceinline__ unsigned short f2bf(float f) {
  union { float f; unsigned int u; } c; c.f = f;
  unsigned int u = c.u;
  unsigned int r = u + 0x7fffu + ((u >> 16) & 1u);   // RNE
  return (unsigned short)(r >> 16);
}

__global__ __launch_bounds__(256) void fuse_weights(
    const float* __restrict__ W1, const float* __restrict__ W2,
    unsigned short* __restrict__ wft) {
  __shared__ float As[64][65];
  __shared__ float Bs[64][65];
  const int t  = threadIdx.x;
  const int k0 = (blockIdx.x >> 2) * 64;
  const int n0 = (blockIdx.x & 3) * 64;
  const int lr = t >> 2;
  const int ls = t & 3;
  const int tk = t >> 4;
  const int tn = t & 15;

  float acc[4][4];
#pragma unroll
  for (int i = 0; i < 4; ++i)
#pragma unroll
    for (int c = 0; c < 4; ++c) acc[i][c] = 0.0f;

  for (int jt = 0; jt < 4; ++jt) {
    const int j0 = jt * 64;
    __syncthreads();
    const float* a_src = W1 + (size_t)(k0 + lr) * H + j0 + ls * 16;
    const float* b_src = W2 + (size_t)(H + j0 + lr) * H + n0 + ls * 16;
#pragma unroll
    for (int i = 0; i < 16; ++i) {
      As[lr][ls * 16 + i] = a_src[i];
      Bs[lr][ls * 16 + i] = b_src[i];
    }
    __syncthreads();
#pragma unroll 8
    for (int j = 0; j < 64; ++j) {
      float a[4], b[4];
#pragma unroll
      for (int i = 0; i < 4; ++i) a[i] = As[tk * 4 + i][j];
#pragma unroll
      for (int c = 0; c < 4; ++c) b[c] = Bs[j][tn * 4 + c];
#pragma unroll
      for (int i = 0; i < 4; ++i)
#pragma unroll
        for (int c = 0; c < 4; ++c) acc[i][c] += a[i] * b[c];
    }
  }

#pragma unroll
  for (int i = 0; i < 4; ++i) {
    const int k = k0 + tk * 4 + i;
#pragma unroll
    for (int c = 0; c < 4; ++c) {
      const int n = n0 + tn * 4 + c;
      float v = acc[i][c];
      if (k < H) v += W2[(size_t)k * H + n];
      wft[(size_t)n * K2 + k] = f2bf(v);
    }
  }
}

__global__ __launch_bounds__(256) void fuse_bias(
    const float* __restrict__ W2, const float* __restrict__ b1,
    const float* __restrict__ b2, float* __restrict__ biasf) {
  const int n = threadIdx.x;
  float acc = b2[n];
  for (int j = 0; j < H; ++j) acc += b1[j] * W2[(size_t)(H + j) * H + n];
  biasf[n] = acc;
}

__global__ __launch_bounds__(NTHR, 3) void syl_main(
    const float* __restrict__ cemb, const int* __restrict__ tal,
    const float* __restrict__ dec, const unsigned short* __restrict__ wft,
    const float* __restrict__ biasf, const float* __restrict__ gamma,
    const float* __restrict__ beta, float* __restrict__ out) {

  // A double-buffer: 2 x 2 x 4 x 64 chunks x 16 B = 16384 B; epilogue reuses
  // as float [16][260] = 16640 B.
  __shared__ __align__(16) char smem[16640];
  unsigned short* AshC = (unsigned short*)smem;
  float* Ef = (float*)smem;

  __shared__ int   idxs[BM];
  __shared__ float msks[BM];
  __shared__ float stats[4][BM][2];

  const int t    = threadIdx.x;
  const int wave = t >> 6;
  const int lane = t & 63;
  const int quad = lane >> 4;
  const int l15  = lane & 15;
  const int row0 = blockIdx.x * BM;
  const int bidx = row0 >> LCSH;
  const float* decb = dec + (size_t)bidx * SDEC * H;

  if (t < BM) {
    int ix = tal[row0 + t];
    idxs[t] = ix < 0 ? 0 : (ix >= SDEC ? SDEC - 1 : ix);
    msks[t] = ix < 0 ? 0.0f : 1.0f;
  }

  f32x4 acc[4][4];
#pragma unroll
  for (int m = 0; m < 4; ++m)
#pragma unroll
    for (int n = 0; n < 4; ++n) acc[m][n] = (f32x4){0.f, 0.f, 0.f, 0.f};

  const int srow = t >> 2;
  const int sseg = t & 3;
  const int ksS  = sseg >> 1;
  const int qS   = (sseg & 1) * 2;
  const int mS   = srow >> 4;
  const int l15S = srow & 15;
  const int wchunk0 = (ksS * 4 + mS) * 64 + qS * 16 + l15S;

  // prologue: stage ki=0 (char half only)
  {
    const float* src = cemb + (size_t)(row0 + srow) * H + sseg * 16;
    float4 f[4];
#pragma unroll
    for (int q = 0; q < 4; ++q) f[q] = *(const float4*)(src + q * 4);
    unsigned short hb[16];
#pragma unroll
    for (int q = 0; q < 4; ++q) {
      hb[q * 4 + 0] = f2bf(f[q].x); hb[q * 4 + 1] = f2bf(f[q].y);
      hb[q * 4 + 2] = f2bf(f[q].z); hb[q * 4 + 3] = f2bf(f[q].w);
    }
    *(short8*)(AshC + (size_t)wchunk0 * 8)        = *(short8*)&hb[0];
    *(short8*)(AshC + (size_t)(wchunk0 + 16) * 8) = *(short8*)&hb[8];
  }
  __syncthreads();

  int buf = 0;
  for (int ki = 0; ki < 8; ++ki) {
    const int k0 = ki * BK;

    // B fragments from global first (their waits leave A-prefetch in flight)
    short8 bf[2][4];
#pragma unroll
    for (int ks = 0; ks < 2; ++ks)
#pragma unroll
      for (int n = 0; n < 4; ++n) {
        const unsigned short* bp =
            wft + (size_t)(wave * 64 + n * 16 + l15) * K2 + k0 + ks * 32 + quad * 8;
        bf[ks][n] = *(const short8*)bp;
      }

    // prefetch next A tile (fp32) into registers
    float4 f[4];
    float scale = 1.0f;
    if (ki < 7) {
      const int k0n = k0 + BK;
      const float* src;
      if (k0n < H) {
        src = cemb + (size_t)(row0 + srow) * H + k0n + sseg * 16;
      } else {
        src = decb + (size_t)idxs[srow] * H + (k0n - H) + sseg * 16;
        scale = msks[srow];
      }
#pragma unroll
      for (int q = 0; q < 4; ++q) f[q] = *(const float4*)(src + q * 4);
    }

    // MFMA on current buffer (linear-in-lane ds_read_b128)
#pragma unroll
    for (int ks = 0; ks < 2; ++ks) {
      short8 af[4];
#pragma unroll
      for (int m = 0; m < 4; ++m)
        af[m] = *(const short8*)(AshC +
                 (size_t)(((buf * 2 + ks) * 4 + m) * 64 + lane) * 8);
#pragma unroll
      for (int n = 0; n < 4; ++n)
#pragma unroll
        for (int m = 0; m < 4; ++m)
          acc[m][n] = __builtin_amdgcn_mfma_f32_16x16x32_bf16(
              af[m], bf[ks][n], acc[m][n], 0, 0, 0);
    }

    // convert + write next buffer, single barrier
    if (ki < 7) {
      unsigned short hb[16];
#pragma unroll
      for (int q = 0; q < 4; ++q) {
        hb[q * 4 + 0] = f2bf(f[q].x * scale); hb[q * 4 + 1] = f2bf(f[q].y * scale);
        hb[q * 4 + 2] = f2bf(f[q].z * scale); hb[q * 4 + 3] = f2bf(f[q].w * scale);
      }
      const int nb = buf ^ 1;
      *(short8*)(AshC + (size_t)(nb * 512 + wchunk0) * 8)      = *(short8*)&hb[0];
      *(short8*)(AshC + (size_t)(nb * 512 + wchunk0 + 16) * 8) = *(short8*)&hb[8];
      __syncthreads();
      buf = nb;
    }
  }

  // epilogue: bias + LN stats
  float bvals[4], gvals[4], betv[4];
#pragma unroll
  for (int n = 0; n < 4; ++n) {
    const int col = wave * 64 + n * 16 + l15;
    bvals[n] = biasf[col];
    gvals[n] = gamma[col];
    betv[n]  = beta[col];
  }
#pragma unroll
  for (int m = 0; m < 4; ++m)
#pragma unroll
    for (int n = 0; n < 4; ++n)
#pragma unroll
      for (int r = 0; r < 4; ++r) acc[m][n][r] += bvals[n];

#pragma unroll
  for (int m = 0; m < 4; ++m)
#pragma unroll
    for (int r = 0; r < 4; ++r) {
      float a = 0.f, b = 0.f;
#pragma unroll
      for (int n = 0; n < 4; ++n) {
        const float v = acc[m][n][r];
        a += v; b += v * v;
      }
#pragma unroll
      for (int d = 1; d < 16; d <<= 1) {
        a += __shfl_xor(a, d, 64);
        b += __shfl_xor(b, d, 64);
      }
      if (l15 == 0) {
        const int row = m * 16 + quad * 4 + r;
        stats[wave][row][0] = a;
        stats[wave][row][1] = b;
      }
    }
  __syncthreads();   // also guards smem reuse (all MFMA ds_reads complete)

  float mean_[4][4], rstd_[4][4];
#pragma unroll
  for (int m = 0; m < 4; ++m)
#pragma unroll
    for (int r = 0; r < 4; ++r) {
      const int row = m * 16 + quad * 4 + r;
      const float a = stats[0][row][0] + stats[1][row][0] +
                      stats[2][row][0] + stats[3][row][0];
      const float b = stats[0][row][1] + stats[1][row][1] +
                      stats[2][row][1] + stats[3][row][1];
      const float mu  = a * (1.0f / 256.0f);
      const float var = b * (1.0f / 256.0f) - mu * mu;
      mean_[m][r] = mu;
      rstd_[m][r] = rsqrtf(var + 1e-5f);
    }

  // LN + GELU + residual via LDS transpose, float4 I/O
  const int erow = t >> 4;
  const int eseg = t & 15;
#pragma unroll
  for (int m = 0; m < 4; ++m) {
#pragma unroll
    for (int r = 0; r < 4; ++r) {
#pragma unroll
      for (int n = 0; n < 4; ++n) {
        const float x = (acc[m][n][r] - mean_[m][r]) * rstd_[m][r];
        const float y = x * gvals[n] + betv[n];
        const float g = 0.5f * y * (1.0f + erff(y * 0.70710678118654752f));
        Ef[(quad * 4 + r) * 260 + wave * 64 + n * 16 + l15] = g;
      }
    }
    __syncthreads();
    {
      const size_t grow = (size_t)row0 + m * 16 + erow;
      const float* crow = cemb + grow * H + eseg * 16;
      float* orow = out + grow * H + eseg * 16;
#pragma unroll
      for (int j = 0; j < 4; ++j) {
        float4 v = *(const float4*)&Ef[erow * 260 + eseg * 16 + j * 4];
        float4 c = *(const float4*)(crow + j * 4);
        v.x += c.x; v.y += c.y; v.z += c.z; v.w += c.w;
        *(float4*)(orow + j * 4) = v;
      }
    }
    __syncthreads();
  }
}

extern "C" void kernel_launch(void* const* d_in, const int* in_sizes, int n_in,
                              void* d_out, int out_size, void* d_ws, size_t ws_size,
                              hipStream_t stream) {
  const float* cemb  = (const float*)d_in[0];
  const int*   tal   = (const int*)d_in[1];
  const float* dec   = (const float*)d_in[2];
  const float* W1    = (const float*)d_in[3];
  const float* b1    = (const float*)d_in[4];
  const float* W2    = (const float*)d_in[5];
  const float* b2    = (const float*)d_in[6];
  const float* gamma = (const float*)d_in[7];
  const float* beta  = (const float*)d_in[8];
  float* out = (float*)d_out;

  unsigned short* wft = (unsigned short*)d_ws;
  float* biasf = (float*)((char*)d_ws + (size_t)K2 * H * sizeof(unsigned short));

  const int rows = in_sizes[0] / H;   // 131072

  hipLaunchKernelGGL(fuse_weights, dim3(32), dim3(256), 0, stream, W1, W2, wft);
  hipLaunchKernelGGL(fuse_bias, dim3(1), dim3(256), 0, stream, W2, b1, b2, biasf);
  hipLaunchKernelGGL(syl_main, dim3(rows / BM), dim3(NTHR), 0, stream,
                     cemb, tal, dec, wft, biasf, gamma, beta, out);
}